// Round 5
// baseline (62286.896 us; speedup 1.0000x reference)
//
#include <hip/hip_runtime.h>

// NeuralCDE: B=64,T=256,C=16,S=64,H=128. fp32 everywhere (R1 showed the ODE
// amplifies per-step error ~1e3; f16 state/weights decorrelate).
// R4 passed at 20.4ms: latency-bound, 13.3us/stage, 64 CUs busy, no overlap.
// R5: 4 blocks per batch element (256 blocks = 256 CUs), each owns 256 rows
// of W2; per-stage k-slice exchange via L2 + per-batch release/acquire
// counter (same-XCD placement: batch = blk&63). W1/W2 slices prefetched into
// registers at stage top (consumed 3 barriers later). W0 in LDS. y,k in regs.

typedef float float4v __attribute__((ext_vector_type(4)));

__device__ __forceinline__ float softplusf(float x) {
  // jax.nn.softplus = max(x,0) + log1p(exp(-|x|))
  return fmaxf(x, 0.f) + log1pf(expf(-fabsf(x)));
}

__device__ __forceinline__ float dot4(float4v a, float4v b) {
  return a.x * b.x + a.y * b.y + a.z * b.z + a.w * b.w;
}

__global__ void init_ws(int* cnt) {
  if (threadIdx.x < 64) cnt[threadIdx.x] = 0;
}

// out6 -> 3x3 rotation write for time index t. Called by all 512 threads of
// the p==0 block.
__device__ __forceinline__ void emit_out(int tid, int t,
                                         const float* sY, const float* sRo,
                                         const float* sRob,
                                         float* __restrict__ outb,
                                         float* s6) {
  if (tid < 96) {
    int o = tid >> 4, ch = (tid & 15) * 4;
    const float* ro = sRo + o * 64 + ch;
    float p = ro[0] * sY[ch] + ro[1] * sY[ch + 1] + ro[2] * sY[ch + 2] +
              ro[3] * sY[ch + 3];
    p += __shfl_xor(p, 1);
    p += __shfl_xor(p, 2);
    p += __shfl_xor(p, 4);
    p += __shfl_xor(p, 8);
    if ((tid & 15) == 0) s6[o] = p + sRob[o];
  }
  __syncthreads();
  if (tid == 0) {
    float a1x = s6[0], a1y = s6[1], a1z = s6[2];
    float a2x = s6[3], a2y = s6[4], a2z = s6[5];
    float n1 = rsqrtf(a1x * a1x + a1y * a1y + a1z * a1z);
    float b1x = a1x * n1, b1y = a1y * n1, b1z = a1z * n1;
    float d = b1x * a2x + b1y * a2y + b1z * a2z;
    float px = a2x - d * b1x, py = a2y - d * b1y, pz = a2z - d * b1z;
    float n2 = rsqrtf(px * px + py * py + pz * pz);
    float b2x = px * n2, b2y = py * n2, b2z = pz * n2;
    float b3x = b1y * b2z - b1z * b2y;
    float b3y = b1z * b2x - b1x * b2z;
    float b3z = b1x * b2y - b1y * b2x;
    float* o = outb + (size_t)t * 9;
    o[0] = b1x; o[1] = b2x; o[2] = b3x;
    o[3] = b1y; o[4] = b2y; o[5] = b3y;
    o[6] = b1z; o[7] = b2z; o[8] = b3z;
  }
}

__global__ __launch_bounds__(512, 2) void cde_main(
    const float* __restrict__ xs,
    const float* __restrict__ icw0, const float* __restrict__ icb0,
    const float* __restrict__ icw1, const float* __restrict__ icb1,
    const float* __restrict__ icw2, const float* __restrict__ icb2,
    const float* __restrict__ vfw0, const float* __restrict__ vfb0,
    const float* __restrict__ vfw1, const float* __restrict__ vfb1,
    const float* __restrict__ vfw2, const float* __restrict__ vfb2,
    const float* __restrict__ row, const float* __restrict__ rob,
    int* __restrict__ cnt, float* __restrict__ kbuf,
    float* __restrict__ out) {
  constexpr float Ac[6][5] = {
      {0.f, 0.f, 0.f, 0.f, 0.f},
      {0.161f, 0.f, 0.f, 0.f, 0.f},
      {-0.008480655492356989f, 0.335480655492357f, 0.f, 0.f, 0.f},
      {2.8971530571054935f, -6.359448489975075f, 4.3622954328695815f, 0.f, 0.f},
      {5.325864828439257f, -11.748883564062828f, 7.4955393428898365f,
       -0.09249506636175525f, 0.f},
      {5.86145544294642f, -12.92096931784711f, 8.159367898576159f,
       -0.071584973281401f, -0.028269050394068383f}};
  constexpr float SCv[6] = {0.f, 0.161f, 0.327f, 0.9f, 0.9800255409045097f, 1.f};
  constexpr float BWv[6] = {0.09646076681806523f, 0.01f, 0.4798896504144996f,
                            1.379008574103742f, -3.290069515436081f,
                            2.324710524099774f};

  const int tid = threadIdx.x;
  const int batch = blockIdx.x & 63;  // members of a group differ by 64 -> same XCD
  const int p = blockIdx.x >> 6;      // 0..3: W2 row-slice owner

  __shared__ __align__(16) float sW0[128 * 68];  // stride-68 pad
  __shared__ float sRo[384], sRob[6];
  __shared__ __align__(16) float sYt[64];
  __shared__ __align__(16) float sH1p[4 * 36];   // 4 chunks of 32, stride 36
  __shared__ __align__(16) float sH2[128];
  __shared__ float sDx[16];
  __shared__ float s6[6];
  __shared__ float sTA[128], sTB[128];

  for (int i = tid; i < 8192; i += 512) sW0[(i >> 6) * 68 + (i & 63)] = vfw0[i];
  if (tid < 384) sRo[tid] = row[tid];
  if (tid < 6) sRob[tid] = rob[tid];

  const float* Xb = xs + (size_t)batch * 256 * 16;
  float* outb = out + (size_t)batch * 256 * 9;
  int* mycnt = cnt + batch;

  // per-thread invariant pointers / scalars
  const int i128 = tid >> 2, q = tid & 3;          // h1/h2 roles
  const float b0i = vfb0[i128];
  const float b1i = vfb1[i128];
  const int r = p * 256 + (tid >> 1);              // W2 row owned
  const int hf = tid & 1;                          // which half of the row
  const float b2r = vfb2[r];
  const float4v* w1p = (const float4v*)(vfw1 + (size_t)i128 * 128 + q * 32);
  const float4v* w2p = (const float4v*)(vfw2 + (size_t)r * 128 + hf * 64);

  __syncthreads();

  // ---- initial condition MLP (redundant per block, deterministic) ----
  if (tid < 128) {
    float a = icb0[tid];
    const float* wr = icw0 + tid * 16;
#pragma unroll
    for (int k = 0; k < 16; ++k) a += wr[k] * Xb[k];
    sTA[tid] = softplusf(a);
  }
  __syncthreads();
  if (tid < 128) {
    float a = icb1[tid];
    const float* wr = icw1 + tid * 128;
    for (int k = 0; k < 128; ++k) a += wr[k] * sTA[k];
    sTB[tid] = softplusf(a);
  }
  __syncthreads();
  float yreg = 0.f;    // valid on tid<64
  float kreg[6];       // valid on tid<64
  if (tid < 64) {
    float a = icb2[tid];
    const float* wr = icw2 + tid * 128;
    for (int k = 0; k < 128; ++k) a += wr[k] * sTB[k];
    yreg = a;
    sYt[tid] = a;
  }
  __syncthreads();
  if (p == 0) emit_out(tid, 0, sYt, sRo, sRob, outb, s6);

  const float hstep = 1.f / 255.f;
  const float invh = 255.f;

  float xi = 0.f, xip1 = 0.f, di = 0.f, dip1 = 0.f;  // valid on tid 64..79

  for (int t = 0; t < 255; ++t) {
    if (tid >= 64 && tid < 80) {
      int c = tid - 64;
      xi = Xb[t * 16 + c];
      xip1 = Xb[(t + 1) * 16 + c];
      dip1 = (xip1 - xi) * invh;
      di = (t == 0) ? dip1 : (xi - Xb[(t - 1) * 16 + c]) * invh;
    }
#pragma unroll
    for (int j = 0; j < 6; ++j) {
      const int g = t * 6 + j;  // global stage index, 0..1529
      // ---- prefetch W1 slice + W2 half-row (consumed 2-3 barriers later) --
      float4v w1r[8];
#pragma unroll
      for (int kk = 0; kk < 8; ++kk) w1r[kk] = w1p[kk];
      float4v w2r[16];
#pragma unroll
      for (int kk = 0; kk < 16; ++kk) w2r[kk] = w2p[kk];
      // ---- phase 0: stage input y_j and dXdt(sc_j) ----
      if (tid < 64) {
        float yt = yreg;
#pragma unroll
        for (int m = 0; m < 5; ++m)
          if (m < j) yt += hstep * Ac[j][m] * kreg[m];
        sYt[tid] = yt;
      } else if (tid < 80) {
        float sc = SCv[j];
        float s2 = sc * sc;
        float d1 = (6.f * s2 - 6.f * sc) * invh;
        float d2 = 3.f * s2 - 4.f * sc + 1.f;
        float d4 = 3.f * s2 - 2.f * sc;
        sDx[tid - 64] = d1 * (xi - xip1) + d2 * di + d4 * dip1;
      }
      __syncthreads();
      // ---- h1 = softplus(W0 @ y + b0): W0 from LDS ----
      {
        const float4v* wr = (const float4v*)(sW0 + i128 * 68 + q * 16);
        const float4v* yv = (const float4v*)(sYt + q * 16);
        float s = 0.f;
#pragma unroll
        for (int kk = 0; kk < 4; ++kk) s += dot4(wr[kk], yv[kk]);
        s += __shfl_xor(s, 1);
        s += __shfl_xor(s, 2);
        if (q == 0) sH1p[(i128 >> 5) * 36 + (i128 & 31)] = softplusf(s + b0i);
      }
      __syncthreads();
      // ---- h2 = softplus(W1 @ h1 + b1): W1 from prefetched regs ----
      {
        const float4v* hv = (const float4v*)(sH1p + q * 36);
        float s = 0.f;
#pragma unroll
        for (int kk = 0; kk < 8; ++kk) s += dot4(w1r[kk], hv[kk]);
        s += __shfl_xor(s, 1);
        s += __shfl_xor(s, 2);
        if (q == 0) sH2[i128] = softplusf(s + b1i);
      }
      __syncthreads();
      // ---- k-slice: A-row dot h2, tanh, * dx, reduce over c ----
      {
        const float4v* hv = (const float4v*)(sH2 + hf * 64);
        float s = 0.f;
#pragma unroll
        for (int kk = 0; kk < 16; ++kk) s += dot4(w2r[kk], hv[kk]);
        s += __shfl_xor(s, 1);  // combine row halves
        float f = tanhf(s + b2r) * sDx[r & 15];
        f += __shfl_xor(f, 2);
        f += __shfl_xor(f, 4);
        f += __shfl_xor(f, 8);
        f += __shfl_xor(f, 16);  // sum over c=16 (bits 1..4 of tid)
        if ((tid & 31) == 0) {
          int sl = tid >> 5;  // 0..15 local state
          kbuf[(((size_t)batch * 2 + (g & 1)) * 4 + p) * 16 + sl] = f;
        }
      }
      __threadfence();   // drain k-slice stores to L2 (device scope)
      __syncthreads();
      // ---- handshake: post + spin (tid 0 only) ----
      if (tid == 0) {
        __hip_atomic_fetch_add(mycnt, 1, __ATOMIC_RELEASE,
                               __HIP_MEMORY_SCOPE_AGENT);
        while (__hip_atomic_load(mycnt, __ATOMIC_ACQUIRE,
                                 __HIP_MEMORY_SCOPE_AGENT) < 4 * (g + 1))
          __builtin_amdgcn_s_sleep(1);
      }
      __syncthreads();
      // ---- gather full k ----
      if (tid < 64) {
        kreg[j] = __hip_atomic_load(
            &kbuf[(((size_t)batch * 2 + (g & 1)) * 4 + (tid >> 4)) * 16 +
                  (tid & 15)],
            __ATOMIC_RELAXED, __HIP_MEMORY_SCOPE_AGENT);
      }
    }
    // ---- y_{t+1} = y_t + h * sum BW_m k_m ----
    if (tid < 64) {
      float yn = yreg;
#pragma unroll
      for (int m = 0; m < 6; ++m) yn += hstep * BWv[m] * kreg[m];
      yreg = yn;
      sYt[tid] = yn;
    }
    if (p == 0) {
      __syncthreads();
      emit_out(tid, t + 1, sYt, sRo, sRob, outb, s6);
    }
  }
}

extern "C" void kernel_launch(void* const* d_in, const int* in_sizes, int n_in,
                              void* d_out, int out_size, void* d_ws,
                              size_t ws_size, hipStream_t stream) {
  (void)in_sizes; (void)n_in; (void)out_size; (void)ws_size;
  const float* xs   = (const float*)d_in[0];
  const float* icw0 = (const float*)d_in[1];
  const float* icb0 = (const float*)d_in[2];
  const float* icw1 = (const float*)d_in[3];
  const float* icb1 = (const float*)d_in[4];
  const float* icw2 = (const float*)d_in[5];
  const float* icb2 = (const float*)d_in[6];
  const float* vfw0 = (const float*)d_in[7];
  const float* vfb0 = (const float*)d_in[8];
  const float* vfw1 = (const float*)d_in[9];
  const float* vfb1 = (const float*)d_in[10];
  const float* vfw2 = (const float*)d_in[11];
  const float* vfb2 = (const float*)d_in[12];
  const float* row  = (const float*)d_in[13];
  const float* rob  = (const float*)d_in[14];

  int* cnt = (int*)d_ws;                 // 64 ints
  float* kbuf = (float*)d_ws + 64;       // [64][2][4][16] floats

  hipLaunchKernelGGL(init_ws, dim3(1), dim3(64), 0, stream, cnt);
  hipLaunchKernelGGL(cde_main, dim3(256), dim3(512), 0, stream,
                     xs, icw0, icb0, icw1, icb1, icw2, icb2,
                     vfw0, vfb0, vfw1, vfb1, vfw2, vfb2, row, rob,
                     cnt, kbuf, (float*)d_out);
}

// Round 6
// 10599.163 us; speedup vs baseline: 5.8766x; 5.8766x over previous
//
#include <hip/hip_runtime.h>

// NeuralCDE: B=64,T=256,C=16,S=64,H=128. fp32 everywhere (R1: f16 anywhere in
// the recursion decorrelates; R4 fp32 passed at bf16 floor 0.0039).
// R4: 20.4ms, latency-bound re-streaming 576KB/stage of loop-invariant
// weights per CU. R5: 4-way model split w/ per-stage cross-block sync = 62ms
// (agent-scope fences force L2 writeback/invalidate per stage; FETCH 6x).
// R6: back to 64 blocks (1 per batch), 1024 threads (16 waves), weights
// mostly CU-resident: W2 cols 0-63 in regs, 64-95 prefetched at stage top,
// 96-127 in LDS (128KB col-major, conflict-free); W0/W1 streamed (96KB).

typedef float float4v __attribute__((ext_vector_type(4)));

__device__ __forceinline__ float softplusf(float x) {
  return fmaxf(x, 0.f) + log1pf(expf(-fabsf(x)));
}

__device__ __forceinline__ float dot4(float4v a, float4v b) {
  return a.x * b.x + a.y * b.y + a.z * b.z + a.w * b.w;
}

// out6 -> 3x3 rotation write for time index t. Called by ALL 1024 threads.
__device__ __forceinline__ void emit_out(int tid, int t,
                                         const float* sY, const float* sRo,
                                         const float* sRob,
                                         float* __restrict__ outb,
                                         float* s6) {
  if (tid < 96) {
    int o = tid >> 4, ch = (tid & 15) * 4;
    const float* ro = sRo + o * 64 + ch;
    float p = ro[0] * sY[ch] + ro[1] * sY[ch + 1] + ro[2] * sY[ch + 2] +
              ro[3] * sY[ch + 3];
    p += __shfl_xor(p, 1);
    p += __shfl_xor(p, 2);
    p += __shfl_xor(p, 4);
    p += __shfl_xor(p, 8);
    if ((tid & 15) == 0) s6[o] = p + sRob[o];
  }
  __syncthreads();
  if (tid == 0) {
    float a1x = s6[0], a1y = s6[1], a1z = s6[2];
    float a2x = s6[3], a2y = s6[4], a2z = s6[5];
    float n1 = rsqrtf(a1x * a1x + a1y * a1y + a1z * a1z);
    float b1x = a1x * n1, b1y = a1y * n1, b1z = a1z * n1;
    float d = b1x * a2x + b1y * a2y + b1z * a2z;
    float px = a2x - d * b1x, py = a2y - d * b1y, pz = a2z - d * b1z;
    float n2 = rsqrtf(px * px + py * py + pz * pz);
    float b2x = px * n2, b2y = py * n2, b2z = pz * n2;
    float b3x = b1y * b2z - b1z * b2y;
    float b3y = b1z * b2x - b1x * b2z;
    float b3z = b1x * b2y - b1y * b2x;
    float* o = outb + (size_t)t * 9;
    o[0] = b1x; o[1] = b2x; o[2] = b3x;
    o[3] = b1y; o[4] = b2y; o[5] = b3y;
    o[6] = b1z; o[7] = b2z; o[8] = b3z;
  }
}

__global__ __launch_bounds__(1024) void cde_main(
    const float* __restrict__ xs,
    const float* __restrict__ icw0, const float* __restrict__ icb0,
    const float* __restrict__ icw1, const float* __restrict__ icb1,
    const float* __restrict__ icw2, const float* __restrict__ icb2,
    const float* __restrict__ vfw0, const float* __restrict__ vfb0,
    const float* __restrict__ vfw1, const float* __restrict__ vfb1,
    const float* __restrict__ vfw2, const float* __restrict__ vfb2,
    const float* __restrict__ row, const float* __restrict__ rob,
    float* __restrict__ out) {
  constexpr float Ac[6][5] = {
      {0.f, 0.f, 0.f, 0.f, 0.f},
      {0.161f, 0.f, 0.f, 0.f, 0.f},
      {-0.008480655492356989f, 0.335480655492357f, 0.f, 0.f, 0.f},
      {2.8971530571054935f, -6.359448489975075f, 4.3622954328695815f, 0.f, 0.f},
      {5.325864828439257f, -11.748883564062828f, 7.4955393428898365f,
       -0.09249506636175525f, 0.f},
      {5.86145544294642f, -12.92096931784711f, 8.159367898576159f,
       -0.071584973281401f, -0.028269050394068383f}};
  constexpr float SCv[6] = {0.f, 0.161f, 0.327f, 0.9f, 0.9800255409045097f, 1.f};
  constexpr float BWv[6] = {0.09646076681806523f, 0.01f, 0.4798896504144996f,
                            1.379008574103742f, -3.290069515436081f,
                            2.324710524099774f};

  const int tid = threadIdx.x;
  const int b = blockIdx.x;  // one block per batch element

  __shared__ float sW2t[32][1024];  // W2 cols 96..127, col-major: 128 KB
  __shared__ float sRo[384], sRob[6];
  __shared__ __align__(16) float sYt[64];
  __shared__ __align__(16) float sH1[128];
  __shared__ __align__(16) float sH2[128];
  __shared__ float sDx[16];
  __shared__ float sK[6][64];
  __shared__ float s6[6];
  __shared__ float sTA[128], sTB[128];

  // ---- one-time loads ----
  for (int i = tid; i < 32 * 1024; i += 1024) {
    int k = i >> 10, r = i & 1023;
    sW2t[k][r] = vfw2[(size_t)r * 128 + 96 + k];
  }
  if (tid < 384) sRo[tid] = row[tid];
  if (tid < 6) sRob[tid] = rob[tid];

  // W2 row `tid`, cols 0..63 resident in registers
  const float4v* w2p = (const float4v*)(vfw2 + (size_t)tid * 128);
  float4v w2res[16];
#pragma unroll
  for (int kk = 0; kk < 16; ++kk) w2res[kk] = w2p[kk];
  const float b2r = vfb2[tid];

  // h1/h2 roles: 8 lanes per output
  const int i8 = tid >> 3, q8 = tid & 7;
  const float b0i = vfb0[i8];
  const float b1i = vfb1[i8];
  const float4v* w0p = (const float4v*)(vfw0 + (size_t)i8 * 64 + q8 * 8);
  const float4v* w1p = (const float4v*)(vfw1 + (size_t)i8 * 128 + q8 * 16);

  const float* Xb = xs + (size_t)b * 256 * 16;
  float* outb = out + (size_t)b * 256 * 9;

  __syncthreads();

  // ---- initial condition MLP (one-time, first 128 threads) ----
  if (tid < 128) {
    float a = icb0[tid];
    const float* wr = icw0 + tid * 16;
#pragma unroll
    for (int k = 0; k < 16; ++k) a += wr[k] * Xb[k];
    sTA[tid] = softplusf(a);
  }
  __syncthreads();
  if (tid < 128) {
    float a = icb1[tid];
    const float* wr = icw1 + tid * 128;
    for (int k = 0; k < 128; ++k) a += wr[k] * sTA[k];
    sTB[tid] = softplusf(a);
  }
  __syncthreads();
  float yreg = 0.f;  // valid on tid<64
  if (tid < 64) {
    float a = icb2[tid];
    const float* wr = icw2 + tid * 128;
    for (int k = 0; k < 128; ++k) a += wr[k] * sTB[k];
    yreg = a;
    sYt[tid] = a;
  }
  __syncthreads();
  emit_out(tid, 0, sYt, sRo, sRob, outb, s6);

  const float hstep = 1.f / 255.f;
  const float invh = 255.f;

  float xi = 0.f, xip1 = 0.f, di = 0.f, dip1 = 0.f;  // valid on tid 64..79

  for (int t = 0; t < 255; ++t) {
    if (tid >= 64 && tid < 80) {
      int c = tid - 64;
      xi = Xb[t * 16 + c];
      xip1 = Xb[(t + 1) * 16 + c];
      dip1 = (xip1 - xi) * invh;
      di = (t == 0) ? dip1 : (xi - Xb[(t - 1) * 16 + c]) * invh;
    }
#pragma unroll 1
    for (int j = 0; j < 6; ++j) {
      // ---- prefetch W2 cols 64..95 of own row (consumed 3 barriers later)
      float4v w2mid[8];
#pragma unroll
      for (int kk = 0; kk < 8; ++kk) w2mid[kk] = w2p[16 + kk];
      // ---- phase 0: stage input y_j and dXdt(sc_j) ----
      if (tid < 64) {
        float yt = yreg;
#pragma unroll
        for (int m = 0; m < 5; ++m)
          if (m < j) yt += hstep * Ac[j][m] * sK[m][tid];
        sYt[tid] = yt;
      } else if (tid < 80) {
        float sc = SCv[j];
        float s2 = sc * sc;
        float d1 = (6.f * s2 - 6.f * sc) * invh;
        float d2 = 3.f * s2 - 4.f * sc + 1.f;
        float d4 = 3.f * s2 - 2.f * sc;
        sDx[tid - 64] = d1 * (xi - xip1) + d2 * di + d4 * dip1;
      }
      __syncthreads();
      // ---- h1 = softplus(W0 @ y + b0): 8 lanes/output, W0 streamed ----
      {
        const float4v* yv = (const float4v*)(sYt + q8 * 8);
        float s = dot4(w0p[0], yv[0]) + dot4(w0p[1], yv[1]);
        s += __shfl_xor(s, 1);
        s += __shfl_xor(s, 2);
        s += __shfl_xor(s, 4);
        if (q8 == 0) sH1[i8] = softplusf(s + b0i);
      }
      __syncthreads();
      // ---- h2 = softplus(W1 @ h1 + b1): W1 streamed ----
      {
        const float4v* hv = (const float4v*)(sH1 + q8 * 16);
        float s = 0.f;
#pragma unroll
        for (int kk = 0; kk < 4; ++kk) s += dot4(w1p[kk], hv[kk]);
        s += __shfl_xor(s, 1);
        s += __shfl_xor(s, 2);
        s += __shfl_xor(s, 4);
        if (q8 == 0) sH2[i8] = softplusf(s + b1i);
      }
      __syncthreads();
      // ---- k: row tid of A = tanh(W2 h2 + b2), times dx, reduce over c ----
      {
        const float4v* hv = (const float4v*)sH2;
        float s = 0.f;
#pragma unroll
        for (int kk = 0; kk < 16; ++kk) s += dot4(w2res[kk], hv[kk]);
#pragma unroll
        for (int kk = 0; kk < 8; ++kk) s += dot4(w2mid[kk], hv[16 + kk]);
#pragma unroll
        for (int k = 0; k < 32; ++k) s += sW2t[k][tid] * sH2[96 + k];
        float f = tanhf(s + b2r) * sDx[tid & 15];
        f += __shfl_xor(f, 1);
        f += __shfl_xor(f, 2);
        f += __shfl_xor(f, 4);
        f += __shfl_xor(f, 8);
        if ((tid & 15) == 0) sK[j][tid >> 4] = f;
      }
      __syncthreads();
    }
    // ---- y_{t+1} = y_t + h * sum BW_m k_m ----
    if (tid < 64) {
      float yn = yreg;
#pragma unroll
      for (int m = 0; m < 6; ++m) yn += hstep * BWv[m] * sK[m][tid];
      yreg = yn;
      sYt[tid] = yn;
    }
    __syncthreads();
    emit_out(tid, t + 1, sYt, sRo, sRob, outb, s6);
  }
}

extern "C" void kernel_launch(void* const* d_in, const int* in_sizes, int n_in,
                              void* d_out, int out_size, void* d_ws,
                              size_t ws_size, hipStream_t stream) {
  (void)in_sizes; (void)n_in; (void)out_size; (void)d_ws; (void)ws_size;
  const float* xs   = (const float*)d_in[0];
  const float* icw0 = (const float*)d_in[1];
  const float* icb0 = (const float*)d_in[2];
  const float* icw1 = (const float*)d_in[3];
  const float* icb1 = (const float*)d_in[4];
  const float* icw2 = (const float*)d_in[5];
  const float* icb2 = (const float*)d_in[6];
  const float* vfw0 = (const float*)d_in[7];
  const float* vfb0 = (const float*)d_in[8];
  const float* vfw1 = (const float*)d_in[9];
  const float* vfb1 = (const float*)d_in[10];
  const float* vfw2 = (const float*)d_in[11];
  const float* vfb2 = (const float*)d_in[12];
  const float* row  = (const float*)d_in[13];
  const float* rob  = (const float*)d_in[14];

  hipLaunchKernelGGL(cde_main, dim3(64), dim3(1024), 0, stream,
                     xs, icw0, icb0, icw1, icb1, icw2, icb2,
                     vfw0, vfb0, vfw1, vfb1, vfw2, vfb2, row, rob,
                     (float*)d_out);
}